// Round 5
// baseline (1056.249 us; speedup 1.0000x reference)
//
#include <hip/hip_runtime.h>
#include <math.h>
#include <stdint.h>

#define S_LEN 8192
#define HID   1280
#define NH    16
#define HD    80
#define LCH   1024
#define NCH   8

typedef __attribute__((ext_vector_type(8))) short bf16x8;
typedef __attribute__((ext_vector_type(4))) float f32x4;

__device__ __forceinline__ uint16_t f2bf(float f) {
    union { float f; uint32_t u; } v; v.f = f;
    uint32_t r = v.u + 0x7FFF + ((v.u >> 16) & 1);   // RNE
    return (uint16_t)(r >> 16);
}
__device__ __forceinline__ float bf2f(uint16_t h) {
    union { uint32_t u; float f; } v; v.u = ((uint32_t)h) << 16;
    return v.f;
}
__device__ __forceinline__ uint16_t f2bf_trunc(float f) {
    union { float f; uint32_t u; } v; v.f = f;
    return (uint16_t)(v.u >> 16);
}

__device__ __forceinline__ void glds16(const void* g, void* l) {
    __builtin_amdgcn_global_load_lds(
        (const __attribute__((address_space(1))) uint32_t*)g,
        (__attribute__((address_space(3))) uint32_t*)l,
        16, 0, 0);
}

#define MFMA16(a, b, c) __builtin_amdgcn_mfma_f32_16x16x32_bf16(a, b, c, 0, 0, 0)

// ---------------- prepass: split x fp32 -> hi/lo bf16 (same layout) ----------------
__global__ __launch_bounds__(256)
void xsplit_kernel(const float* __restrict__ x, uint16_t* __restrict__ xh,
                   uint16_t* __restrict__ xl)
{
    int idx = (blockIdx.x * 256 + threadIdx.x) * 4;
    float4 v = *(const float4*)(x + idx);
    ushort4 hi, lo;
    hi.x = f2bf(v.x); lo.x = f2bf(v.x - bf2f(hi.x));
    hi.y = f2bf(v.y); lo.y = f2bf(v.y - bf2f(hi.y));
    hi.z = f2bf(v.z); lo.z = f2bf(v.z - bf2f(hi.z));
    hi.w = f2bf(v.w); lo.w = f2bf(v.w - bf2f(hi.w));
    *(ushort4*)(xh + idx) = hi;
    *(ushort4*)(xl + idx) = lo;
}

// ---------------- prepass: W [1280][ND] fp32 -> W^T [ND][1280] hi/lo bf16 ----------------
template<int ND>
__global__ __launch_bounds__(256)
void wsplit_kernel(const float* __restrict__ W, uint16_t* __restrict__ Wth,
                   uint16_t* __restrict__ Wtl)
{
    __shared__ float t[32][33];
    const int tid = threadIdx.x;
    const int n0 = blockIdx.x * 32;
    const int k0 = blockIdx.y * 32;
    for (int i = tid; i < 1024; i += 256) {
        int r = i >> 5, c = i & 31;
        t[r][c] = W[(size_t)(k0 + r) * ND + n0 + c];
    }
    __syncthreads();
    for (int i = tid; i < 1024; i += 256) {
        int r = i >> 5, c = i & 31;          // r: n offset, c: k offset
        float f = t[c][r];
        uint16_t hi = f2bf(f);
        size_t o = (size_t)(n0 + r) * HID + k0 + c;
        Wth[o] = hi;
        Wtl[o] = f2bf(f - bf2f(hi));
    }
}

// ---------------- LDS-free split-bf16 MFMA GEMM: C = A @ B^T (+bias) ----------------
// A,Bt row-major along K -> 16x16x32 fragments are 16 contiguous bytes/lane in
// global. Each wave loads fragments straight global->VGPR, double-buffered one
// K-step ahead. No __syncthreads in the K-loop: compiler emits fine-grained
// s_waitcnt vmcnt(N), prefetch loads stay in flight across the MFMA block
// (AITER-style). Cross-wave duplicate fragment reads hit L1 (waves co-resident).
template<int ND, int EPI>
__global__ __launch_bounds__(256)
void mfma_gemm_reg(const uint16_t* __restrict__ Ah, const uint16_t* __restrict__ Al,
                   const uint16_t* __restrict__ Bth, const uint16_t* __restrict__ Btl,
                   const float* __restrict__ bias, float* __restrict__ oF,
                   uint16_t* __restrict__ oq, uint16_t* __restrict__ ok,
                   uint16_t* __restrict__ ov)
{
    const int tid  = threadIdx.x;
    const int w    = tid >> 6;
    const int lane = tid & 63;
    const int quad = lane >> 4;
    const int l16  = lane & 15;
    const int wm   = w >> 1;
    const int wn   = w & 1;

    const int n0 = blockIdx.x * 128;
    const int m0 = blockIdx.y * 128;

    // per-lane byte offsets of each fragment at kt=0
    uint32_t aoff[4], boff[4];
    #pragma unroll
    for (int mi = 0; mi < 4; ++mi)
        aoff[mi] = (uint32_t)(m0 + wm * 64 + mi * 16 + l16) * (HID * 2) + quad * 16;
    #pragma unroll
    for (int ni = 0; ni < 4; ++ni)
        boff[ni] = (uint32_t)(n0 + wn * 64 + ni * 16 + l16) * (HID * 2) + quad * 16;

    const char* Ahc = (const char*)Ah;
    const char* Alc = (const char*)Al;
    const char* Bhc = (const char*)Bth;
    const char* Blc = (const char*)Btl;

    f32x4 acc[4][4];
    #pragma unroll
    for (int i = 0; i < 4; i++)
        #pragma unroll
        for (int j = 0; j < 4; j++) acc[i][j] = (f32x4){0.f, 0.f, 0.f, 0.f};

    bf16x8 cah[4], cal[4], cbh[4], cbl[4];   // current K-step fragments
    bf16x8 nah[4], nal[4], nbh[4], nbl[4];   // next K-step fragments

#define LOADF(dah, dal, dbh, dbl, KB)                                   \
    do {                                                                \
        _Pragma("unroll") for (int mi = 0; mi < 4; ++mi) {              \
            dah[mi] = *(const bf16x8*)(Ahc + aoff[mi] + (KB));          \
            dal[mi] = *(const bf16x8*)(Alc + aoff[mi] + (KB));          \
        }                                                               \
        _Pragma("unroll") for (int ni = 0; ni < 4; ++ni) {              \
            dbh[ni] = *(const bf16x8*)(Bhc + boff[ni] + (KB));          \
            dbl[ni] = *(const bf16x8*)(Blc + boff[ni] + (KB));          \
        }                                                               \
    } while (0)

#define COMPUTE(pah, pal, pbh, pbl)                                     \
    do {                                                                \
        _Pragma("unroll") for (int mi = 0; mi < 4; ++mi)                \
        _Pragma("unroll") for (int ni = 0; ni < 4; ++ni) {              \
            acc[mi][ni] = MFMA16(pah[mi], pbh[ni], acc[mi][ni]);        \
            acc[mi][ni] = MFMA16(pah[mi], pbl[ni], acc[mi][ni]);        \
            acc[mi][ni] = MFMA16(pal[mi], pbh[ni], acc[mi][ni]);        \
        }                                                               \
    } while (0)

    LOADF(cah, cal, cbh, cbl, 0);
    // K=1280 -> 40 steps of BK=32 (64 bytes), unrolled by 2
    for (int kt = 0; kt < 40; kt += 2) {
        LOADF(nah, nal, nbh, nbl, 64);                     // kt+1 in flight
        COMPUTE(cah, cal, cbh, cbl);                       // compute kt
        const uint32_t k2 = (kt + 2 < 40) ? 128u : 0u;     // clamp tail (no OOB)
        LOADF(cah, cal, cbh, cbl, k2);                     // kt+2 in flight
        COMPUTE(nah, nal, nbh, nbl);                       // compute kt+1
        #pragma unroll
        for (int mi = 0; mi < 4; ++mi) aoff[mi] += 128;
        #pragma unroll
        for (int ni = 0; ni < 4; ++ni) boff[ni] += 128;
    }
#undef LOADF
#undef COMPUTE

    // epilogue: D row = quad*4+r (m), col = l16 (n)
    #pragma unroll
    for (int ni = 0; ni < 4; ++ni) {
        const int n = n0 + wn * 64 + ni * 16 + l16;
        const float bv = bias[n];
        #pragma unroll
        for (int mi = 0; mi < 4; ++mi) {
            const int mb = m0 + wm * 64 + mi * 16 + quad * 4;
            if (EPI) {
                int t   = n / HID;
                int rem = n - t * HID;
                int h   = rem / HD;
                int d   = rem - h * HD;
                if (t == 2) {
                    ushort4 pv;
                    pv.x = f2bf(acc[mi][ni][0] + bv);
                    pv.y = f2bf(acc[mi][ni][1] + bv);
                    pv.z = f2bf(acc[mi][ni][2] + bv);
                    pv.w = f2bf(acc[mi][ni][3] + bv);
                    *(ushort4*)&ov[((size_t)h * HD + d) * S_LEN + mb] = pv;
                } else {
                    uint16_t* dst = (t == 0) ? oq : ok;
                    #pragma unroll
                    for (int r = 0; r < 4; ++r)
                        dst[((size_t)h * S_LEN + (mb + r)) * HD + d] =
                            f2bf(acc[mi][ni][r] + bv);
                }
            } else {
                #pragma unroll
                for (int r = 0; r < 4; ++r)
                    oF[(size_t)(mb + r) * ND + n] = acc[mi][ni][r] + bv;
            }
        }
    }
}

// ---------------- rope: in-place on bf16 q and k, layout [h][s][80] ----------------
__global__ __launch_bounds__(256)
void rope_kernel(uint16_t* __restrict__ qb, uint16_t* __restrict__ kb,
                 const float* __restrict__ cosb, const float* __restrict__ sinb)
{
    int idx = blockIdx.x * 256 + threadIdx.x;
    int d = idx % 40;
    int t = idx / 40;
    int s = t % S_LEN;
    int h = t / S_LEN;
    size_t base = ((size_t)h * S_LEN + s) * HD;
    float c1 = cosb[s * HD + d],      s1 = sinb[s * HD + d];
    float c2 = cosb[s * HD + d + 40], s2 = sinb[s * HD + d + 40];
    float q1 = bf2f(qb[base + d]), q2 = bf2f(qb[base + d + 40]);
    qb[base + d]      = f2bf(q1 * c1 - q2 * s1);
    qb[base + d + 40] = f2bf(q2 * c2 + q1 * s2);
    float k1 = bf2f(kb[base + d]), k2 = bf2f(kb[base + d + 40]);
    kb[base + d]      = f2bf(k1 * c1 - k2 * s1);
    kb[base + d + 40] = f2bf(k2 * c2 + k1 * s2);
}

// ---------------- MFMA flash attention, BQ=128 ----------------
#define BQ 128
#define BK 64

__global__ __launch_bounds__(256)
void attn_kernel(const uint16_t* __restrict__ qb, const uint16_t* __restrict__ kb,
                 const uint16_t* __restrict__ vt,
                 uint16_t* __restrict__ abh, uint16_t* __restrict__ abl)
{
    __shared__ __align__(16) uint16_t qs[BQ][HD];
    __shared__ __align__(16) uint16_t ks[BK][HD];
    __shared__ __align__(16) uint16_t vs[96][BK];
    __shared__ __align__(16) uint16_t ps[4][32][68];

    const int tid  = threadIdx.x;
    const int w    = tid >> 6;
    const int lane = tid & 63;
    const int quad = lane >> 4;
    const int l16  = lane & 15;

    const int qt = blockIdx.x;
    const int h  = blockIdx.y;
    const int c  = blockIdx.z;
    const int q0 = c * LCH + qt * BQ;

    {
        const char* qg = (const char*)(qb + ((size_t)h * S_LEN + q0) * HD);
        for (int off = w * 1024; off < BQ * HD * 2; off += 4096)
            glds16(qg + off + lane * 16, (char*)&qs[0][0] + off);
    }
    for (int i = tid; i < 16 * BK; i += 256) {
        int rr = i >> 6;
        int cc = i & 63;
        vs[80 + rr][cc] = (rr == 0) ? 0x3F80 : 0;
    }
    __syncthreads();

    bf16x8 qfr[2][3];
    #pragma unroll
    for (int mi = 0; mi < 2; ++mi) {
        const int row = w * 32 + mi * 16 + l16;
        qfr[mi][0] = *(const bf16x8*)&qs[row][quad * 8];
        qfr[mi][1] = *(const bf16x8*)&qs[row][32 + quad * 8];
        bf16x8 z = {0, 0, 0, 0, 0, 0, 0, 0};
        qfr[mi][2] = (quad < 2) ? *(const bf16x8*)&qs[row][64 + quad * 8] : z;
    }

    f32x4 Oacc[2][6];
    #pragma unroll
    for (int mi = 0; mi < 2; ++mi)
        #pragma unroll
        for (int d = 0; d < 6; d++) Oacc[mi][d] = (f32x4){0.f, 0.f, 0.f, 0.f};

    const float C2 = 0.11180339887498949f * 1.4426950408889634f;
    const char* kg0 = (const char*)(kb + ((size_t)h * S_LEN + c * LCH) * HD);
    const size_t vrow_stride = (size_t)S_LEN * 2;
    const char* vg0 = (const char*)vt + (size_t)h * HD * S_LEN * 2 + (size_t)(c * LCH) * 2;

    for (int kt = 0; kt < LCH / BK; ++kt) {
        __syncthreads();
        {
            const char* kg = kg0 + (size_t)kt * BK * HD * 2;
            for (int off = w * 1024; off < BK * HD * 2; off += 4096)
                glds16(kg + off + lane * 16, (char*)&ks[0][0] + off);
        }
        {
            const char* vg = vg0 + (size_t)(kt * BK) * 2;
            for (int off = w * 1024; off < HD * BK * 2; off += 4096) {
                int o   = off + lane * 16;
                int row = o >> 7;
                int col = o & 127;
                glds16(vg + (size_t)row * vrow_stride + col, (char*)&vs[0][0] + off);
            }
        }
        __syncthreads();

        f32x4 sc[2][4];
        #pragma unroll
        for (int mi = 0; mi < 2; ++mi)
            #pragma unroll
            for (int ns = 0; ns < 4; ns++) sc[mi][ns] = (f32x4){0.f, 0.f, 0.f, 0.f};
        #pragma unroll
        for (int ns = 0; ns < 4; ++ns) {
            const int kr = ns * 16 + l16;
            bf16x8 kf0 = *(const bf16x8*)&ks[kr][quad * 8];
            bf16x8 kf1 = *(const bf16x8*)&ks[kr][32 + quad * 8];
            bf16x8 z = {0, 0, 0, 0, 0, 0, 0, 0};
            bf16x8 kf2 = (quad < 2) ? *(const bf16x8*)&ks[kr][64 + quad * 8] : z;
            #pragma unroll
            for (int mi = 0; mi < 2; ++mi) {
                sc[mi][ns] = MFMA16(qfr[mi][0], kf0, sc[mi][ns]);
                sc[mi][ns] = MFMA16(qfr[mi][1], kf1, sc[mi][ns]);
                sc[mi][ns] = MFMA16(qfr[mi][2], kf2, sc[mi][ns]);
            }
        }

        #pragma unroll
        for (int mi = 0; mi < 2; ++mi)
            #pragma unroll
            for (int r = 0; r < 4; ++r) {
                const int prow = mi * 16 + quad * 4 + r;
                #pragma unroll
                for (int ns = 0; ns < 4; ++ns)
                    ps[w][prow][ns * 16 + l16] =
                        f2bf_trunc(exp2f(sc[mi][ns][r] * C2));
            }

        #pragma unroll
        for (int kc = 0; kc < 2; ++kc) {
            bf16x8 pf[2];
            #pragma unroll
            for (int mi = 0; mi < 2; ++mi) {
                const uint16_t* pp = &ps[w][mi * 16 + l16][kc * 32 + quad * 8];
                ((uint2*)&pf[mi])[0] = *(const uint2*)(pp);
                ((uint2*)&pf[mi])[1] = *(const uint2*)(pp + 4);
            }
            #pragma unroll
            for (int ds = 0; ds < 6; ++ds) {
                bf16x8 vf = *(const bf16x8*)&vs[ds * 16 + l16][kc * 32 + quad * 8];
                #pragma unroll
                for (int mi = 0; mi < 2; ++mi)
                    Oacc[mi][ds] = MFMA16(pf[mi], vf, Oacc[mi][ds]);
            }
        }
    }

    #pragma unroll
    for (int mi = 0; mi < 2; ++mi)
        #pragma unroll
        for (int r = 0; r < 4; ++r) {
            float l = __shfl(Oacc[mi][5][r], lane & 48);
            float inv = 1.f / l;
            const int srow = q0 + w * 32 + mi * 16 + quad * 4 + r;
            const size_t rowbase = (size_t)srow * HID + h * HD;
            #pragma unroll
            for (int ds = 0; ds < 5; ++ds) {
                float f = Oacc[mi][ds][r] * inv;
                uint16_t hi = f2bf(f);
                abh[rowbase + ds * 16 + l16] = hi;
                abl[rowbase + ds * 16 + l16] = f2bf(f - bf2f(hi));
            }
        }
}

extern "C" void kernel_launch(void* const* d_in, const int* in_sizes, int n_in,
                              void* d_out, int out_size, void* d_ws, size_t ws_size,
                              hipStream_t stream)
{
    const float* x     = (const float*)d_in[0];
    const float* cosb  = (const float*)d_in[1];
    const float* sinb  = (const float*)d_in[2];
    const float* Wqkv  = (const float*)d_in[3];
    const float* bqkv  = (const float*)d_in[4];
    const float* Wproj = (const float*)d_in[5];
    const float* bproj = (const float*)d_in[6];
    float* out = (float*)d_out;

    const size_t E = (size_t)NH * S_LEN * HD;   // 10,485,760 (= S*HID)
    uint16_t* qb  = (uint16_t*)d_ws;            // [h][s][80]
    uint16_t* kb  = qb + E;                     // [h][s][80]
    uint16_t* vt  = kb + E;                     // [h][80][s]
    uint16_t* xh  = vt + E;                     // x_hi [s][1280]; later ab_hi
    uint16_t* xl  = xh + E;                     // x_lo;           later ab_lo
    uint16_t* wth = xl + E;                     // W^T hi
    uint16_t* wtl = wth + (size_t)3 * HID * HID;

    xsplit_kernel<<<(S_LEN * HID) / (256 * 4), 256, 0, stream>>>(x, xh, xl);
    wsplit_kernel<3 * HID><<<dim3(3 * HID / 32, HID / 32), 256, 0, stream>>>(Wqkv, wth, wtl);
    mfma_gemm_reg<3 * HID, 1><<<dim3(3 * HID / 128, S_LEN / 128), 256, 0, stream>>>(
        xh, xl, wth, wtl, bqkv, nullptr, qb, kb, vt);
    rope_kernel<<<(S_LEN * NH * 40) / 256, 256, 0, stream>>>(qb, kb, cosb, sinb);
    attn_kernel<<<dim3(LCH / BQ, NH, NCH), 256, 0, stream>>>(qb, kb, vt, xh, xl);
    wsplit_kernel<HID><<<dim3(HID / 32, HID / 32), 256, 0, stream>>>(Wproj, wth, wtl);
    mfma_gemm_reg<HID, 0><<<dim3(HID / 128, S_LEN / 128), 256, 0, stream>>>(
        xh, xl, wth, wtl, bproj, out, nullptr, nullptr, nullptr);
}

// Round 6
// 593.659 us; speedup vs baseline: 1.7792x; 1.7792x over previous
//
#include <hip/hip_runtime.h>
#include <math.h>
#include <stdint.h>

#define S_LEN 8192
#define HID   1280
#define NH    16
#define HD    80
#define LCH   1024
#define NCH   8

typedef __attribute__((ext_vector_type(8))) short bf16x8;
typedef __attribute__((ext_vector_type(4))) float f32x4;

__device__ __forceinline__ uint16_t f2bf(float f) {
    union { float f; uint32_t u; } v; v.f = f;
    uint32_t r = v.u + 0x7FFF + ((v.u >> 16) & 1);   // RNE
    return (uint16_t)(r >> 16);
}
__device__ __forceinline__ float bf2f(uint16_t h) {
    union { uint32_t u; float f; } v; v.u = ((uint32_t)h) << 16;
    return v.f;
}
__device__ __forceinline__ uint16_t f2bf_trunc(float f) {
    union { float f; uint32_t u; } v; v.f = f;
    return (uint16_t)(v.u >> 16);
}

__device__ __forceinline__ void glds16(const void* g, void* l) {
    __builtin_amdgcn_global_load_lds(
        (const __attribute__((address_space(1))) uint32_t*)g,
        (__attribute__((address_space(3))) uint32_t*)l,
        16, 0, 0);
}

#define MFMA16(a, b, c) __builtin_amdgcn_mfma_f32_16x16x32_bf16(a, b, c, 0, 0, 0)

// ---------------- prepass: split x fp32 -> hi/lo bf16 (same layout) ----------------
__global__ __launch_bounds__(256)
void xsplit_kernel(const float* __restrict__ x, uint16_t* __restrict__ xh,
                   uint16_t* __restrict__ xl)
{
    int idx = (blockIdx.x * 256 + threadIdx.x) * 4;
    float4 v = *(const float4*)(x + idx);
    ushort4 hi, lo;
    hi.x = f2bf(v.x); lo.x = f2bf(v.x - bf2f(hi.x));
    hi.y = f2bf(v.y); lo.y = f2bf(v.y - bf2f(hi.y));
    hi.z = f2bf(v.z); lo.z = f2bf(v.z - bf2f(hi.z));
    hi.w = f2bf(v.w); lo.w = f2bf(v.w - bf2f(hi.w));
    *(ushort4*)(xh + idx) = hi;
    *(ushort4*)(xl + idx) = lo;
}

// ---------------- prepass: W [1280][ND] fp32 -> W^T [ND][1280] hi/lo bf16 ----------------
template<int ND>
__global__ __launch_bounds__(256)
void wsplit_kernel(const float* __restrict__ W, uint16_t* __restrict__ Wth,
                   uint16_t* __restrict__ Wtl)
{
    __shared__ float t[32][33];
    const int tid = threadIdx.x;
    const int n0 = blockIdx.x * 32;
    const int k0 = blockIdx.y * 32;
    for (int i = tid; i < 1024; i += 256) {
        int r = i >> 5, c = i & 31;
        t[r][c] = W[(size_t)(k0 + r) * ND + n0 + c];
    }
    __syncthreads();
    for (int i = tid; i < 1024; i += 256) {
        int r = i >> 5, c = i & 31;          // r: n offset, c: k offset
        float f = t[c][r];
        uint16_t hi = f2bf(f);
        size_t o = (size_t)(n0 + r) * HID + k0 + c;
        Wth[o] = hi;
        Wtl[o] = f2bf(f - bf2f(hi));
    }
}

// ---------------- split-bf16 MFMA GEMM: C = A @ B^T (+bias) ----------------
// (round-4 version — known 267 us / ~905 TF; the m97-structure plateau)
template<int ND, int EPI>
__global__ __launch_bounds__(256)
void mfma_gemm_bt(const uint16_t* __restrict__ Ah, const uint16_t* __restrict__ Al,
                  const uint16_t* __restrict__ Bth, const uint16_t* __restrict__ Btl,
                  const float* __restrict__ bias, float* __restrict__ oF,
                  uint16_t* __restrict__ oq, uint16_t* __restrict__ ok,
                  uint16_t* __restrict__ ov)
{
    __shared__ __align__(16) uint16_t Ash[128 * 32];
    __shared__ __align__(16) uint16_t Asl[128 * 32];
    __shared__ __align__(16) uint16_t Bsh[128 * 32];
    __shared__ __align__(16) uint16_t Bsl[128 * 32];

    const int tid  = threadIdx.x;
    const int w    = tid >> 6;
    const int lane = tid & 63;
    const int quad = lane >> 4;
    const int l16  = lane & 15;
    const int wm   = w >> 1;
    const int wn   = w & 1;

    const int n0 = blockIdx.x * 128;
    const int m0 = blockIdx.y * 128;

    const size_t laneoff = (size_t)(lane >> 2) * (HID * 2) + (lane & 3) * 16;
    const char* Agh = (const char*)Ah  + (size_t)m0 * (HID * 2) + laneoff;
    const char* Agl = (const char*)Al  + (size_t)m0 * (HID * 2) + laneoff;
    const char* Bgh = (const char*)Bth + (size_t)n0 * (HID * 2) + laneoff;
    const char* Bgl = (const char*)Btl + (size_t)n0 * (HID * 2) + laneoff;
    const size_t c0off = (size_t)(w * 16) * (HID * 2);
    const size_t c1off = (size_t)((w + 4) * 16) * (HID * 2);
    char* AshB = (char*)Ash; char* AslB = (char*)Asl;
    char* BshB = (char*)Bsh; char* BslB = (char*)Bsl;
    const int l0 = w * 1024, l1 = (w + 4) * 1024;

    f32x4 acc[4][4];
    #pragma unroll
    for (int i = 0; i < 4; i++)
        #pragma unroll
        for (int j = 0; j < 4; j++) acc[i][j] = (f32x4){0.f, 0.f, 0.f, 0.f};

    for (int kt = 0; kt < HID / 32; ++kt) {
        __syncthreads();
        const size_t ko = (size_t)kt * 64;
        glds16(Agh + c0off + ko, AshB + l0);
        glds16(Agh + c1off + ko, AshB + l1);
        glds16(Agl + c0off + ko, AslB + l0);
        glds16(Agl + c1off + ko, AslB + l1);
        glds16(Bgh + c0off + ko, BshB + l0);
        glds16(Bgh + c1off + ko, BshB + l1);
        glds16(Bgl + c0off + ko, BslB + l0);
        glds16(Bgl + c1off + ko, BslB + l1);
        __syncthreads();

        bf16x8 ah[4], al[4], bh[4], bl[4];
        #pragma unroll
        for (int mi = 0; mi < 4; ++mi) {
            const int row = wm * 64 + mi * 16 + l16;
            ah[mi] = *(const bf16x8*)&Ash[row * 32 + quad * 8];
            al[mi] = *(const bf16x8*)&Asl[row * 32 + quad * 8];
        }
        #pragma unroll
        for (int ni = 0; ni < 4; ++ni) {
            const int row = wn * 64 + ni * 16 + l16;
            bh[ni] = *(const bf16x8*)&Bsh[row * 32 + quad * 8];
            bl[ni] = *(const bf16x8*)&Bsl[row * 32 + quad * 8];
        }
        #pragma unroll
        for (int mi = 0; mi < 4; ++mi)
            #pragma unroll
            for (int ni = 0; ni < 4; ++ni) {
                acc[mi][ni] = MFMA16(ah[mi], bh[ni], acc[mi][ni]);
                acc[mi][ni] = MFMA16(ah[mi], bl[ni], acc[mi][ni]);
                acc[mi][ni] = MFMA16(al[mi], bh[ni], acc[mi][ni]);
            }
    }

    #pragma unroll
    for (int ni = 0; ni < 4; ++ni) {
        const int n = n0 + wn * 64 + ni * 16 + l16;
        const float bv = bias[n];
        #pragma unroll
        for (int mi = 0; mi < 4; ++mi) {
            const int mb = m0 + wm * 64 + mi * 16 + quad * 4;
            if (EPI) {
                int t   = n / HID;
                int rem = n - t * HID;
                int h   = rem / HD;
                int d   = rem - h * HD;
                if (t == 2) {
                    ushort4 pv;
                    pv.x = f2bf(acc[mi][ni][0] + bv);
                    pv.y = f2bf(acc[mi][ni][1] + bv);
                    pv.z = f2bf(acc[mi][ni][2] + bv);
                    pv.w = f2bf(acc[mi][ni][3] + bv);
                    *(ushort4*)&ov[((size_t)h * HD + d) * S_LEN + mb] = pv;
                } else {
                    uint16_t* dst = (t == 0) ? oq : ok;
                    #pragma unroll
                    for (int r = 0; r < 4; ++r)
                        dst[((size_t)h * S_LEN + (mb + r)) * HD + d] =
                            f2bf(acc[mi][ni][r] + bv);
                }
            } else {
                #pragma unroll
                for (int r = 0; r < 4; ++r)
                    oF[(size_t)(mb + r) * ND + n] = acc[mi][ni][r] + bv;
            }
        }
    }
}

// ---------------- rope: in-place on bf16 q and k, layout [h][s][80] ----------------
__global__ __launch_bounds__(256)
void rope_kernel(uint16_t* __restrict__ qb, uint16_t* __restrict__ kb,
                 const float* __restrict__ cosb, const float* __restrict__ sinb)
{
    int idx = blockIdx.x * 256 + threadIdx.x;
    int d = idx % 40;
    int t = idx / 40;
    int s = t % S_LEN;
    int h = t / S_LEN;
    size_t base = ((size_t)h * S_LEN + s) * HD;
    float c1 = cosb[s * HD + d],      s1 = sinb[s * HD + d];
    float c2 = cosb[s * HD + d + 40], s2 = sinb[s * HD + d + 40];
    float q1 = bf2f(qb[base + d]), q2 = bf2f(qb[base + d + 40]);
    qb[base + d]      = f2bf(q1 * c1 - q2 * s1);
    qb[base + d + 40] = f2bf(q2 * c2 + q1 * s2);
    float k1 = bf2f(kb[base + d]), k2 = bf2f(kb[base + d + 40]);
    kb[base + d]      = f2bf(k1 * c1 - k2 * s1);
    kb[base + d + 40] = f2bf(k2 * c2 + k1 * s2);
}

// ---------------- MFMA flash attention, BQ=128, covered-drain pipeline ----------------
// K double-buffered, V single-buffered. Per ktile:
//   barrier A (K(kt) ready, drain covered by PV(kt-1)) -> issue V(kt) -> QK
//   barrier B (V(kt) ready, drain covered by QK)        -> issue K(kt+1) -> PV
// ps aliases the dead Q-staging region; ones-column V slab lives in registers.
#define BQ 128
#define BK 64

__global__ __launch_bounds__(256)
void attn_kernel(const uint16_t* __restrict__ qb, const uint16_t* __restrict__ kb,
                 const uint16_t* __restrict__ vt,
                 uint16_t* __restrict__ abh, uint16_t* __restrict__ abl)
{
    __shared__ __align__(16) uint16_t smemA[BQ * HD];     // Q staging, then ps
    __shared__ __align__(16) uint16_t ksm[2][BK * HD];    // K tiles, dbuf (10240 B each)
    __shared__ __align__(16) uint16_t vsm[HD * BK];       // V tile [d][key] (10240 B)

    const int tid  = threadIdx.x;
    const int w    = tid >> 6;
    const int lane = tid & 63;
    const int quad = lane >> 4;
    const int l16  = lane & 15;

    const int qt = blockIdx.x;
    const int h  = blockIdx.y;
    const int c  = blockIdx.z;
    const int q0 = c * LCH + qt * BQ;

    uint16_t (*psw)[68] = (uint16_t(*)[68])smemA + w * 32;   // per-wave 32x68 (fits dead Q region)

    // stage Q tile into region A
    {
        const char* qg = (const char*)(qb + ((size_t)h * S_LEN + q0) * HD);
        for (int off = w * 1024; off < BQ * HD * 2; off += 4096)
            glds16(qg + off + lane * 16, (char*)smemA + off);
    }
    __syncthreads();   // Q staged (drains vmcnt)

    bf16x8 qfr[2][3];
    #pragma unroll
    for (int mi = 0; mi < 2; ++mi) {
        const int row = w * 32 + mi * 16 + l16;
        qfr[mi][0] = *(const bf16x8*)&smemA[row * HD + quad * 8];
        qfr[mi][1] = *(const bf16x8*)&smemA[row * HD + 32 + quad * 8];
        bf16x8 z = {0, 0, 0, 0, 0, 0, 0, 0};
        qfr[mi][2] = (quad < 2) ? *(const bf16x8*)&smemA[row * HD + 64 + quad * 8] : z;
    }

    // ones-column V fragment for the l-accumulator slab (registers, not LDS)
    bf16x8 vf5;
    {
        short o = (l16 == 0) ? (short)0x3F80 : (short)0;
        vf5 = (bf16x8){o, o, o, o, o, o, o, o};
    }

    f32x4 Oacc[2][6];
    #pragma unroll
    for (int mi = 0; mi < 2; ++mi)
        #pragma unroll
        for (int d = 0; d < 6; d++) Oacc[mi][d] = (f32x4){0.f, 0.f, 0.f, 0.f};

    const float C2 = 0.11180339887498949f * 1.4426950408889634f;  // 1/sqrt(80) * log2(e)
    const char* kg0 = (const char*)(kb + ((size_t)h * S_LEN + c * LCH) * HD);
    const size_t vrow_stride = (size_t)S_LEN * 2;
    const char* vg0 = (const char*)vt + (size_t)h * HD * S_LEN * 2 + (size_t)(c * LCH) * 2;

    // prefetch K(0) into buffer 0
    {
        const char* kg = kg0;
        for (int off = w * 1024; off < BK * HD * 2; off += 4096)
            glds16(kg + off + lane * 16, (char*)&ksm[0][0] + off);
    }

    for (int kt = 0; kt < LCH / BK; ++kt) {
        __syncthreads();   // barrier A: K(kt) staged; PV(kt-1)/qfr reads done

        // issue V(kt) (in flight across QK)
        {
            const char* vg = vg0 + (size_t)(kt * BK) * 2;
            for (int off = w * 1024; off < HD * BK * 2; off += 4096) {
                int o   = off + lane * 16;
                int row = o >> 7;
                int col = o & 127;
                glds16(vg + (size_t)row * vrow_stride + col, (char*)vsm + off);
            }
        }

        // ---- S = Q K^T from ksm[kt&1] ----
        const uint16_t* ksb = &ksm[kt & 1][0];
        f32x4 sc[2][4];
        #pragma unroll
        for (int mi = 0; mi < 2; ++mi)
            #pragma unroll
            for (int ns = 0; ns < 4; ns++) sc[mi][ns] = (f32x4){0.f, 0.f, 0.f, 0.f};
        #pragma unroll
        for (int ns = 0; ns < 4; ++ns) {
            const int kr = ns * 16 + l16;
            bf16x8 kf0 = *(const bf16x8*)&ksb[kr * HD + quad * 8];
            bf16x8 kf1 = *(const bf16x8*)&ksb[kr * HD + 32 + quad * 8];
            bf16x8 z = {0, 0, 0, 0, 0, 0, 0, 0};
            bf16x8 kf2 = (quad < 2) ? *(const bf16x8*)&ksb[kr * HD + 64 + quad * 8] : z;
            #pragma unroll
            for (int mi = 0; mi < 2; ++mi) {
                sc[mi][ns] = MFMA16(qfr[mi][0], kf0, sc[mi][ns]);
                sc[mi][ns] = MFMA16(qfr[mi][1], kf1, sc[mi][ns]);
                sc[mi][ns] = MFMA16(qfr[mi][2], kf2, sc[mi][ns]);
            }
        }

        // ---- no-max softmax -> ps (per-wave region) ----
        #pragma unroll
        for (int mi = 0; mi < 2; ++mi)
            #pragma unroll
            for (int r = 0; r < 4; ++r) {
                const int prow = mi * 16 + quad * 4 + r;
                #pragma unroll
                for (int ns = 0; ns < 4; ++ns)
                    psw[prow][ns * 16 + l16] =
                        f2bf_trunc(exp2f(sc[mi][ns][r] * C2));
            }

        __syncthreads();   // barrier B: V(kt) staged (drain covered by QK)

        // issue K(kt+1) into the other buffer (in flight across PV)
        if (kt + 1 < LCH / BK) {
            const char* kg = kg0 + (size_t)(kt + 1) * BK * HD * 2;
            char* dst = (char*)&ksm[(kt + 1) & 1][0];
            for (int off = w * 1024; off < BK * HD * 2; off += 4096)
                glds16(kg + off + lane * 16, dst + off);
        }

        // ---- O += P V ----
        #pragma unroll
        for (int kc = 0; kc < 2; ++kc) {
            bf16x8 pf[2];
            #pragma unroll
            for (int mi = 0; mi < 2; ++mi) {
                const uint16_t* pp = &psw[mi * 16 + l16][kc * 32 + quad * 8];
                ((uint2*)&pf[mi])[0] = *(const uint2*)(pp);
                ((uint2*)&pf[mi])[1] = *(const uint2*)(pp + 4);
            }
            #pragma unroll
            for (int ds = 0; ds < 5; ++ds) {
                bf16x8 vf = *(const bf16x8*)&vsm[(ds * 16 + l16) * BK + kc * 32 + quad * 8];
                #pragma unroll
                for (int mi = 0; mi < 2; ++mi)
                    Oacc[mi][ds] = MFMA16(pf[mi], vf, Oacc[mi][ds]);
            }
            #pragma unroll
            for (int mi = 0; mi < 2; ++mi)
                Oacc[mi][5] = MFMA16(pf[mi], vf5, Oacc[mi][5]);
        }
    }

    // epilogue: l = ones-column (col 0 of slab 5); O/l -> split hi/lo bf16 ab
    #pragma unroll
    for (int mi = 0; mi < 2; ++mi)
        #pragma unroll
        for (int r = 0; r < 4; ++r) {
            float l = __shfl(Oacc[mi][5][r], lane & 48);
            float inv = 1.f / l;
            const int srow = q0 + w * 32 + mi * 16 + quad * 4 + r;
            const size_t rowbase = (size_t)srow * HID + h * HD;
            #pragma unroll
            for (int ds = 0; ds < 5; ++ds) {
                float f = Oacc[mi][ds][r] * inv;
                uint16_t hi = f2bf(f);
                abh[rowbase + ds * 16 + l16] = hi;
                abl[rowbase + ds * 16 + l16] = f2bf(f - bf2f(hi));
            }
        }
}

extern "C" void kernel_launch(void* const* d_in, const int* in_sizes, int n_in,
                              void* d_out, int out_size, void* d_ws, size_t ws_size,
                              hipStream_t stream)
{
    const float* x     = (const float*)d_in[0];
    const float* cosb  = (const float*)d_in[1];
    const float* sinb  = (const float*)d_in[2];
    const float* Wqkv  = (const float*)d_in[3];
    const float* bqkv  = (const float*)d_in[4];
    const float* Wproj = (const float*)d_in[5];
    const float* bproj = (const float*)d_in[6];
    float* out = (float*)d_out;

    const size_t E = (size_t)NH * S_LEN * HD;   // 10,485,760 (= S*HID)
    uint16_t* qb  = (uint16_t*)d_ws;            // [h][s][80]
    uint16_t* kb  = qb + E;                     // [h][s][80]
    uint16_t* vt  = kb + E;                     // [h][80][s]
    uint16_t* xh  = vt + E;                     // x_hi [s][1280]; later ab_hi
    uint16_t* xl  = xh + E;                     // x_lo;           later ab_lo
    uint16_t* wth = xl + E;                     // W^T hi
    uint16_t* wtl = wth + (size_t)3 * HID * HID;

    xsplit_kernel<<<(S_LEN * HID) / (256 * 4), 256, 0, stream>>>(x, xh, xl);
    wsplit_kernel<3 * HID><<<dim3(3 * HID / 32, HID / 32), 256, 0, stream>>>(Wqkv, wth, wtl);
    mfma_gemm_bt<3 * HID, 1><<<dim3(3 * HID / 128, S_LEN / 128), 256, 0, stream>>>(
        xh, xl, wth, wtl, bqkv, nullptr, qb, kb, vt);
    rope_kernel<<<(S_LEN * NH * 40) / 256, 256, 0, stream>>>(qb, kb, cosb, sinb);
    attn_kernel<<<dim3(LCH / BQ, NH, NCH), 256, 0, stream>>>(qb, kb, vt, xh, xl);
    wsplit_kernel<HID><<<dim3(HID / 32, HID / 32), 256, 0, stream>>>(Wproj, wth, wtl);
    mfma_gemm_bt<HID, 0><<<dim3(HID / 128, S_LEN / 128), 256, 0, stream>>>(
        xh, xl, wth, wtl, bproj, out, nullptr, nullptr, nullptr);
}